// Round 1
// baseline (11995.338 us; speedup 1.0000x reference)
//
#include <hip/hip_runtime.h>

#define T_LEN 4000
#define BATCH 32
#define NMELS 40
#define CONDC 64
#define GRUH  96
#define NPITCH 360

typedef float f2v __attribute__((ext_vector_type(2)));

__device__ __forceinline__ float sigmoid_f(float x) {
    return 1.f / (1.f + __expf(-x));
}
__device__ __forceinline__ float tanh_f(float x) {
    // tanh(x) = 1 - 2/(1+exp(2x)); exact at +-inf, ~1e-7 rel error
    return 1.f - 2.f / (1.f + __expf(2.f * x));
}

// ---------------------------------------------------------------------------
// conv1: mel (B,T,40) -> c1T (B,64,T), causal k=3 pad-left-2, tanh
// block: (t-tile 64) x batch. 256 threads: lanes = t, 4 groups x 16 oc.
// ---------------------------------------------------------------------------
__global__ void conv1_kernel(const float* __restrict__ mel,
                             const float* __restrict__ w,   // (64,40,3)
                             const float* __restrict__ bias,
                             float* __restrict__ outT) {    // (B,64,T)
    __shared__ float lds[NMELS * 66];
    const int b  = blockIdx.y;
    const int t0 = blockIdx.x * 64;
    const int tid = threadIdx.x;
    for (int idx = tid; idx < 66 * NMELS; idx += 256) {
        int ic = idx % NMELS, trow = idx / NMELS;
        int tg = t0 - 2 + trow;
        float v = (tg >= 0 && tg < T_LEN) ? mel[((size_t)b * T_LEN + tg) * NMELS + ic] : 0.f;
        lds[ic * 66 + trow] = v;
    }
    __syncthreads();
    const int lane = tid & 63;
    const int g = tid >> 6;   // 0..3, wave-uniform
    float acc[16];
#pragma unroll
    for (int i = 0; i < 16; ++i) acc[i] = bias[g * 16 + i];
#pragma unroll
    for (int kk = 0; kk < 3; ++kk) {
        for (int ic = 0; ic < NMELS; ++ic) {
            float m = lds[ic * 66 + lane + kk];
#pragma unroll
            for (int i = 0; i < 16; ++i)
                acc[i] = fmaf(w[((g * 16 + i) * NMELS + ic) * 3 + kk], m, acc[i]);
        }
    }
    int t = t0 + lane;
    if (t < T_LEN) {
#pragma unroll
        for (int i = 0; i < 16; ++i)
            outT[((size_t)b * CONDC + g * 16 + i) * T_LEN + t] = tanh_f(acc[i]);
    }
}

// ---------------------------------------------------------------------------
// conv2: c1T (B,64,T) -> xT (B,96,T), causal k=3, tanh
// 256 threads: lanes = t, 4 groups x 24 oc.
// ---------------------------------------------------------------------------
__global__ void conv2_kernel(const float* __restrict__ inT,  // (B,64,T)
                             const float* __restrict__ w,    // (96,64,3)
                             const float* __restrict__ bias,
                             float* __restrict__ outT) {     // (B,96,T)
    __shared__ float lds[CONDC * 66];
    const int b  = blockIdx.y;
    const int t0 = blockIdx.x * 64;
    const int tid = threadIdx.x;
    for (int idx = tid; idx < 66 * CONDC; idx += 256) {
        int trow = idx % 66, ic = idx / 66;
        int tg = t0 - 2 + trow;
        float v = (tg >= 0 && tg < T_LEN) ? inT[((size_t)b * CONDC + ic) * T_LEN + tg] : 0.f;
        lds[ic * 66 + trow] = v;
    }
    __syncthreads();
    const int lane = tid & 63;
    const int g = tid >> 6;
    float acc[24];
#pragma unroll
    for (int i = 0; i < 24; ++i) acc[i] = bias[g * 24 + i];
#pragma unroll
    for (int kk = 0; kk < 3; ++kk) {
        for (int ic = 0; ic < CONDC; ++ic) {
            float m = lds[ic * 66 + lane + kk];
#pragma unroll
            for (int i = 0; i < 24; ++i)
                acc[i] = fmaf(w[((g * 24 + i) * CONDC + ic) * 3 + kk], m, acc[i]);
        }
    }
    int t = t0 + lane;
    if (t < T_LEN) {
#pragma unroll
        for (int i = 0; i < 24; ++i)
            outT[((size_t)b * GRUH + g * 24 + i) * T_LEN + t] = tanh_f(acc[i]);
    }
}

// ---------------------------------------------------------------------------
// xp = in @ wih^T + bih  -> (B,T,288)
// lanes = j (288 outputs), 32 timesteps per block; weights in VGPR chunks,
// activations via wave-uniform loads (scalar cache).
// ---------------------------------------------------------------------------
__global__ __launch_bounds__(288) void xp_kernel(
    const float* __restrict__ in,   // transposed: (B,96,T); else (B,T,96)
    const float* __restrict__ wih,  // (288,96)
    const float* __restrict__ bih,  // (288)
    float* __restrict__ xp,         // (B,T,288)
    int in_transposed) {
    const int b  = blockIdx.y;
    const int t0 = blockIdx.x * 32;
    const int j  = threadIdx.x;
    float acc[32];
    const float bj = bih[j];
#pragma unroll
    for (int tt = 0; tt < 32; ++tt) acc[tt] = bj;
    for (int kc = 0; kc < GRUH; kc += 16) {
        float wr[16];
#pragma unroll
        for (int q = 0; q < 16; ++q) wr[q] = wih[j * GRUH + kc + q];
        if (in_transposed) {
#pragma unroll
            for (int tt = 0; tt < 32; ++tt) {
                int t = t0 + tt;
#pragma unroll
                for (int q = 0; q < 16; ++q)
                    acc[tt] = fmaf(wr[q], in[((size_t)b * GRUH + kc + q) * T_LEN + t], acc[tt]);
            }
        } else {
#pragma unroll
            for (int tt = 0; tt < 32; ++tt) {
                int t = t0 + tt;
#pragma unroll
                for (int q = 0; q < 16; ++q)
                    acc[tt] = fmaf(wr[q], in[((size_t)b * T_LEN + t) * GRUH + kc + q], acc[tt]);
            }
        }
    }
#pragma unroll
    for (int tt = 0; tt < 32; ++tt)
        xp[((size_t)b * T_LEN + t0 + tt) * 288 + j] = acc[tt];
}

// ---------------------------------------------------------------------------
// GRU recurrence for one layer. 32 blocks (1 per batch) x 288 threads.
// Thread j owns whh row j in 96 VGPRs; h broadcast from LDS.
// ---------------------------------------------------------------------------
__global__ __launch_bounds__(288, 1) void gru_rec_kernel(
    const float* __restrict__ xp,   // (B,T,288)
    const float* __restrict__ whh,  // (288,96)
    const float* __restrict__ bhh,  // (288)
    float* __restrict__ g,          // (B,T,96)
    float* __restrict__ hout) {     // (B,96)
    const int b = blockIdx.x;
    const int j = threadIdx.x;
    __shared__ __align__(16) float hbuf[GRUH];
    __shared__ float s_hp[288];
    __shared__ float s_x[288];
    float4 w4[24];
    const float4* wrow = (const float4*)(whh + j * GRUH);
#pragma unroll
    for (int q = 0; q < 24; ++q) w4[q] = wrow[q];
    const float bj = bhh[j];
    if (j < GRUH) hbuf[j] = 0.f;
    const float* xprow = xp + (size_t)b * T_LEN * 288 + j;
    float xq = xprow[0];
    float* grow = g + (size_t)b * T_LEN * GRUH;
    __syncthreads();
    for (int t = 0; t < T_LEN; ++t) {
        const float4* h4 = (const float4*)hbuf;
        f2v a0 = {bj, 0.f};
        f2v a1 = {0.f, 0.f};
#pragma unroll
        for (int q = 0; q < 24; ++q) {
            float4 hv = h4[q];
            float4 wv = w4[q];
            f2v wa = {wv.x, wv.y}, wb = {wv.z, wv.w};
            f2v ha = {hv.x, hv.y}, hb = {hv.z, hv.w};
            a0 = __builtin_elementwise_fma(wa, ha, a0);
            a1 = __builtin_elementwise_fma(wb, hb, a1);
        }
        float hp = (a0.x + a1.x) + (a0.y + a1.y);
        s_hp[j] = hp;
        s_x[j]  = xq;
        __syncthreads();
        int tn = (t + 1 < T_LEN) ? t + 1 : t;
        xq = xprow[(size_t)tn * 288];  // prefetch next step's input projection
        if (j < GRUH) {
            float r = sigmoid_f(s_x[j] + s_hp[j]);
            float z = sigmoid_f(s_x[j + GRUH] + s_hp[j + GRUH]);
            float n = tanh_f(s_x[j + 2 * GRUH] + r * s_hp[j + 2 * GRUH]);
            float h = hbuf[j];
            h = n + z * (h - n);
            hbuf[j] = h;
            grow[(size_t)t * GRUH + j] = h;
        }
        __syncthreads();
    }
    if (j < GRUH) hout[b * GRUH + j] = hbuf[j];
}

// ---------------------------------------------------------------------------
// head: cat = [x, g1, g2, g3] (B,T,384); vad = sig(cat@vad_w^T+b),
// pitch = sig(cat@pitch_w^T+b). lane j: j==0 -> vad row, 1..360 -> pitch row.
// ---------------------------------------------------------------------------
__global__ __launch_bounds__(384) void head_kernel(
    const float* __restrict__ xT,   // (B,96,T)
    const float* __restrict__ g1,   // (B,T,96)
    const float* __restrict__ g2,
    const float* __restrict__ g3,
    const float* __restrict__ vad_w, const float* __restrict__ vad_b,
    const float* __restrict__ pitch_w, const float* __restrict__ pitch_b,
    float* __restrict__ vad_out,    // (B,T)
    float* __restrict__ pitch_out) {// (B,T,360)
    const int b  = blockIdx.y;
    const int t0 = blockIdx.x * 32;
    const int j  = threadIdx.x;
    if (j >= 361) return;
    const float* wrow = (j == 0) ? vad_w : pitch_w + (size_t)(j - 1) * 384;
    const float bias = (j == 0) ? vad_b[0] : pitch_b[j - 1];
    float acc[32];
#pragma unroll
    for (int tt = 0; tt < 32; ++tt) acc[tt] = bias;
    // x part (channel-major layout)
    for (int kc = 0; kc < 96; kc += 8) {
        float wr[8];
#pragma unroll
        for (int q = 0; q < 8; ++q) wr[q] = wrow[kc + q];
#pragma unroll
        for (int tt = 0; tt < 32; ++tt) {
            int t = t0 + tt;
#pragma unroll
            for (int q = 0; q < 8; ++q)
                acc[tt] = fmaf(wr[q], xT[((size_t)b * 96 + kc + q) * T_LEN + t], acc[tt]);
        }
    }
    const float* gs[3] = {g1, g2, g3};
    for (int gi = 0; gi < 3; ++gi) {
        const float* gp = gs[gi] + (size_t)b * T_LEN * 96;
        const int kbase = 96 + gi * 96;
        for (int kc = 0; kc < 96; kc += 8) {
            float wr[8];
#pragma unroll
            for (int q = 0; q < 8; ++q) wr[q] = wrow[kbase + kc + q];
#pragma unroll
            for (int tt = 0; tt < 32; ++tt) {
                int t = t0 + tt;
#pragma unroll
                for (int q = 0; q < 8; ++q)
                    acc[tt] = fmaf(wr[q], gp[(size_t)t * 96 + kc + q], acc[tt]);
            }
        }
    }
#pragma unroll
    for (int tt = 0; tt < 32; ++tt) {
        float v = sigmoid_f(acc[tt]);
        int t = t0 + tt;
        if (j == 0) vad_out[(size_t)b * T_LEN + t] = v;
        else        pitch_out[((size_t)b * T_LEN + t) * NPITCH + (j - 1)] = v;
    }
}

extern "C" void kernel_launch(void* const* d_in, const int* in_sizes, int n_in,
                              void* d_out, int out_size, void* d_ws, size_t ws_size,
                              hipStream_t stream) {
    const float* mel = (const float*)d_in[0];
    const float* c1w = (const float*)d_in[1];
    const float* c1b = (const float*)d_in[2];
    const float* c2w = (const float*)d_in[3];
    const float* c2b = (const float*)d_in[4];
    const float* wih[3] = {(const float*)d_in[5],  (const float*)d_in[9],  (const float*)d_in[13]};
    const float* whh[3] = {(const float*)d_in[6],  (const float*)d_in[10], (const float*)d_in[14]};
    const float* bih[3] = {(const float*)d_in[7],  (const float*)d_in[11], (const float*)d_in[15]};
    const float* bhh[3] = {(const float*)d_in[8],  (const float*)d_in[12], (const float*)d_in[16]};
    const float* vad_w   = (const float*)d_in[17];
    const float* vad_b   = (const float*)d_in[18];
    const float* pitch_w = (const float*)d_in[19];
    const float* pitch_b = (const float*)d_in[20];

    float* out       = (float*)d_out;
    float* vad_out   = out;                          // 128000
    float* pitch_out = out + 128000;                 // 46,080,000
    float* hout      = out + 128000 + 46080000;      // 3 x 3072

    // workspace: xT | g1 | g2 | g3 (c1T overlaid on g3; c1T dead before g3 written)
    float* ws  = (float*)d_ws;
    float* xT  = ws;                                 // 12,288,000 floats
    float* g1  = ws + 12288000;
    float* g2  = g1 + 12288000;
    float* g3  = g2 + 12288000;
    float* c1T = g3;                                 // 8,192,000 floats (overlap)
    // xp scratch lives in the pitch output region (written only by head at the end)
    float* xp  = pitch_out;                          // needs 36,864,000 <= 46,080,000

    conv1_kernel<<<dim3(63, 32), 256, 0, stream>>>(mel, c1w, c1b, c1T);
    conv2_kernel<<<dim3(63, 32), 256, 0, stream>>>(c1T, c2w, c2b, xT);

    const float* gin[3] = {xT, g1, g2};
    float*       gou[3] = {g1, g2, g3};
    for (int L = 0; L < 3; ++L) {
        xp_kernel<<<dim3(125, 32), 288, 0, stream>>>(gin[L], wih[L], bih[L], xp, L == 0 ? 1 : 0);
        gru_rec_kernel<<<32, 288, 0, stream>>>(xp, whh[L], bhh[L], gou[L], hout + L * 3072);
    }

    head_kernel<<<dim3(125, 32), 384, 0, stream>>>(xT, g1, g2, g3,
                                                   vad_w, vad_b, pitch_w, pitch_b,
                                                   vad_out, pitch_out);
}

// Round 2
// 10539.569 us; speedup vs baseline: 1.1381x; 1.1381x over previous
//
#include <hip/hip_runtime.h>

#define T_LEN 4000
#define BATCH 32
#define NMELS 40
#define CONDC 64
#define GRUH  96
#define NPITCH 360

typedef float f2v __attribute__((ext_vector_type(2)));

__device__ __forceinline__ float sigmoid_f(float x) {
    return 1.f / (1.f + __expf(-x));
}
__device__ __forceinline__ float tanh_f(float x) {
    return 1.f - 2.f / (1.f + __expf(2.f * x));
}

// ---------------------------------------------------------------------------
// conv1: mel (B,T,40) -> c1T (B,64,T), causal k=3, tanh  (unchanged)
// ---------------------------------------------------------------------------
__global__ void conv1_kernel(const float* __restrict__ mel,
                             const float* __restrict__ w,
                             const float* __restrict__ bias,
                             float* __restrict__ outT) {
    __shared__ float lds[NMELS * 66];
    const int b  = blockIdx.y;
    const int t0 = blockIdx.x * 64;
    const int tid = threadIdx.x;
    for (int idx = tid; idx < 66 * NMELS; idx += 256) {
        int ic = idx % NMELS, trow = idx / NMELS;
        int tg = t0 - 2 + trow;
        float v = (tg >= 0 && tg < T_LEN) ? mel[((size_t)b * T_LEN + tg) * NMELS + ic] : 0.f;
        lds[ic * 66 + trow] = v;
    }
    __syncthreads();
    const int lane = tid & 63;
    const int g = tid >> 6;
    float acc[16];
#pragma unroll
    for (int i = 0; i < 16; ++i) acc[i] = bias[g * 16 + i];
#pragma unroll
    for (int kk = 0; kk < 3; ++kk) {
        for (int ic = 0; ic < NMELS; ++ic) {
            float m = lds[ic * 66 + lane + kk];
#pragma unroll
            for (int i = 0; i < 16; ++i)
                acc[i] = fmaf(w[((g * 16 + i) * NMELS + ic) * 3 + kk], m, acc[i]);
        }
    }
    int t = t0 + lane;
    if (t < T_LEN) {
#pragma unroll
        for (int i = 0; i < 16; ++i)
            outT[((size_t)b * CONDC + g * 16 + i) * T_LEN + t] = tanh_f(acc[i]);
    }
}

// ---------------------------------------------------------------------------
// conv2: c1T (B,64,T) -> xT (B,96,T)  (unchanged)
// ---------------------------------------------------------------------------
__global__ void conv2_kernel(const float* __restrict__ inT,
                             const float* __restrict__ w,
                             const float* __restrict__ bias,
                             float* __restrict__ outT) {
    __shared__ float lds[CONDC * 66];
    const int b  = blockIdx.y;
    const int t0 = blockIdx.x * 64;
    const int tid = threadIdx.x;
    for (int idx = tid; idx < 66 * CONDC; idx += 256) {
        int trow = idx % 66, ic = idx / 66;
        int tg = t0 - 2 + trow;
        float v = (tg >= 0 && tg < T_LEN) ? inT[((size_t)b * CONDC + ic) * T_LEN + tg] : 0.f;
        lds[ic * 66 + trow] = v;
    }
    __syncthreads();
    const int lane = tid & 63;
    const int g = tid >> 6;
    float acc[24];
#pragma unroll
    for (int i = 0; i < 24; ++i) acc[i] = bias[g * 24 + i];
#pragma unroll
    for (int kk = 0; kk < 3; ++kk) {
        for (int ic = 0; ic < CONDC; ++ic) {
            float m = lds[ic * 66 + lane + kk];
#pragma unroll
            for (int i = 0; i < 24; ++i)
                acc[i] = fmaf(w[((g * 24 + i) * CONDC + ic) * 3 + kk], m, acc[i]);
        }
    }
    int t = t0 + lane;
    if (t < T_LEN) {
#pragma unroll
        for (int i = 0; i < 24; ++i)
            outT[((size_t)b * GRUH + g * 24 + i) * T_LEN + t] = tanh_f(acc[i]);
    }
}

// ---------------------------------------------------------------------------
// pack whh (288,96) -> wpack[192][144]: thread pair (p,kh) owns rows
// {p, 96+p, 192+p} k-range [48kh,48kh+48)
// ---------------------------------------------------------------------------
__global__ void pack_whh_kernel(const float* __restrict__ whh,
                                float* __restrict__ wpack) {
    int e = blockIdx.x * 256 + threadIdx.x;
    if (e >= 192 * 144) return;
    int th = e / 144, r = (e % 144) / 48, kk = e % 48;
    int p = th >> 1, kh = th & 1;
    wpack[e] = whh[(r * 96 + p) * 96 + kh * 48 + kk];
}

// ---------------------------------------------------------------------------
// xp = in @ wih^T + bih -> (B,T,288). 96 threads, 3 rows/thread, tile tt=16.
// ---------------------------------------------------------------------------
__global__ __launch_bounds__(96) void xp2_kernel(
    const float* __restrict__ in,   // transposed: (B,96,T) else (B,T,96)
    const float* __restrict__ wih,  // (288,96)
    const float* __restrict__ bih,
    float* __restrict__ xp,         // (B,T,288)
    int in_transposed) {
    __shared__ __align__(16) float al[16][104];
    const int b  = blockIdx.y;
    const int t0 = blockIdx.x * 16;
    const int tid = threadIdx.x;   // 0..95

    if (in_transposed) {
        int ttl = tid & 15, cg = tid >> 4;   // 16 x 6
        for (int k = cg; k < 96; k += 6)
            al[ttl][k] = in[((size_t)b * 96 + k) * T_LEN + t0 + ttl];
    } else {
        for (int i = tid; i < 16 * 96; i += 96) {
            int tt = i / 96;
            al[tt][tid] = in[((size_t)b * T_LEN + t0 + tt) * 96 + tid];
        }
    }
    __syncthreads();

    const float4* w0 = (const float4*)(wih + (size_t)tid * 96);
    const float4* w1 = (const float4*)(wih + (size_t)(96 + tid) * 96);
    const float4* w2 = (const float4*)(wih + (size_t)(192 + tid) * 96);

    f2v acc[3][16];
#pragma unroll
    for (int r = 0; r < 3; ++r)
#pragma unroll
        for (int tt = 0; tt < 16; ++tt) acc[r][tt] = (f2v){0.f, 0.f};

    for (int kc = 0; kc < 24; ++kc) {
        float4 wa = w0[kc], wb = w1[kc], wc = w2[kc];
        f2v wa0 = {wa.x, wa.y}, wa1 = {wa.z, wa.w};
        f2v wb0 = {wb.x, wb.y}, wb1 = {wb.z, wb.w};
        f2v wc0 = {wc.x, wc.y}, wc1 = {wc.z, wc.w};
#pragma unroll
        for (int tt = 0; tt < 16; ++tt) {
            float4 av = *(const float4*)&al[tt][kc * 4];
            f2v a0 = {av.x, av.y}, a1 = {av.z, av.w};
            acc[0][tt] = __builtin_elementwise_fma(wa0, a0, acc[0][tt]);
            acc[0][tt] = __builtin_elementwise_fma(wa1, a1, acc[0][tt]);
            acc[1][tt] = __builtin_elementwise_fma(wb0, a0, acc[1][tt]);
            acc[1][tt] = __builtin_elementwise_fma(wb1, a1, acc[1][tt]);
            acc[2][tt] = __builtin_elementwise_fma(wc0, a0, acc[2][tt]);
            acc[2][tt] = __builtin_elementwise_fma(wc1, a1, acc[2][tt]);
        }
    }
    float b0 = bih[tid], b1 = bih[96 + tid], b2 = bih[192 + tid];
#pragma unroll
    for (int tt = 0; tt < 16; ++tt) {
        size_t base = ((size_t)b * T_LEN + t0 + tt) * 288;
        xp[base + tid]       = acc[0][tt].x + acc[0][tt].y + b0;
        xp[base + 96 + tid]  = acc[1][tt].x + acc[1][tt].y + b1;
        xp[base + 192 + tid] = acc[2][tt].x + acc[2][tt].y + b2;
    }
}

// ---------------------------------------------------------------------------
// GRU recurrence v2: 32 blocks x 192 threads. Pair (2p,2p+1) owns rows
// {p,96+p,192+p} split over k-halves. One lgkm-only barrier per step.
// ---------------------------------------------------------------------------
__global__ __launch_bounds__(192, 1) void gru2_kernel(
    const float* __restrict__ xp,     // (B,T,288)
    const float* __restrict__ wpack,  // (192,144)
    const float* __restrict__ bhh,    // (288)
    float* __restrict__ g,            // (B,T,96)
    float* __restrict__ hout) {       // (B,96)
    const int b = blockIdx.x;
    const int tid = threadIdx.x;
    const int p = tid >> 1, kh = tid & 1;
    __shared__ __align__(16) float hb[2][96];

    float4 w4[36];
    const float4* wp = (const float4*)(wpack + (size_t)tid * 144);
#pragma unroll
    for (int q = 0; q < 36; ++q) {
        float4 w = wp[q];
        asm volatile("" : "+v"(w.x), "+v"(w.y), "+v"(w.z), "+v"(w.w));
        w4[q] = w;
    }
    const float m = (kh == 0) ? 1.f : 0.f;
    const float bhr = bhh[p] * m, bhz = bhh[96 + p] * m, bhn = bhh[192 + p] * m;

    if (tid < 96) hb[0][tid] = 0.f;
    const float* xpb = xp + (size_t)b * T_LEN * 288;
    float xr = xpb[p], xz = xpb[96 + p], xn = xpb[192 + p];
    float hreg = 0.f;
    float* grow = g + (size_t)b * T_LEN * GRUH;
    __syncthreads();

    for (int t = 0; t < T_LEN; ++t) {
        const float4* h4 = (const float4*)(hb[t & 1]) + kh * 12;
        f2v ar = {bhr, 0.f}, az = {bhz, 0.f}, an = {bhn, 0.f};
#pragma unroll
        for (int q = 0; q < 12; ++q) {
            float4 hv = h4[q];
            f2v h0 = {hv.x, hv.y}, h1 = {hv.z, hv.w};
            float4 wr_ = w4[q], wz_ = w4[12 + q], wn_ = w4[24 + q];
            ar = __builtin_elementwise_fma((f2v){wr_.x, wr_.y}, h0, ar);
            ar = __builtin_elementwise_fma((f2v){wr_.z, wr_.w}, h1, ar);
            az = __builtin_elementwise_fma((f2v){wz_.x, wz_.y}, h0, az);
            az = __builtin_elementwise_fma((f2v){wz_.z, wz_.w}, h1, az);
            an = __builtin_elementwise_fma((f2v){wn_.x, wn_.y}, h0, an);
            an = __builtin_elementwise_fma((f2v){wn_.z, wn_.w}, h1, an);
        }
        float hr = ar.x + ar.y, hz = az.x + az.y, hn = an.x + an.y;
        hr += __shfl_xor(hr, 1);
        hz += __shfl_xor(hz, 1);
        hn += __shfl_xor(hn, 1);

        // prefetch next step's xp (stays in flight across the lgkm-only barrier)
        int tn = (t < T_LEN - 1) ? t + 1 : t;
        float xr_n = xpb[(size_t)tn * 288 + p];
        float xz_n = xpb[(size_t)tn * 288 + 96 + p];
        float xn_n = xpb[(size_t)tn * 288 + 192 + p];

        float r = sigmoid_f(xr + hr);
        float z = sigmoid_f(xz + hz);
        float n = tanh_f(xn + r * hn);
        hreg = n + z * (hreg - n);
        if (kh == 0) {
            hb[(t & 1) ^ 1][p] = hreg;
            grow[(size_t)t * GRUH + p] = hreg;
        }
        xr = xr_n; xz = xz_n; xn = xn_n;

        asm volatile("s_waitcnt lgkmcnt(0)" ::: "memory");
        __builtin_amdgcn_s_barrier();
        asm volatile("" ::: "memory");
    }
    if (kh == 0) hout[b * GRUH + p] = hreg;
}

// ---------------------------------------------------------------------------
// head v2: cat=[x,g1,g2,g3] (384); 96 threads, 4 rows/thread, tile tt=8.
// ---------------------------------------------------------------------------
__global__ __launch_bounds__(96) void head2_kernel(
    const float* __restrict__ xT,   // (B,96,T)
    const float* __restrict__ g1,   // (B,T,96)
    const float* __restrict__ g2,
    const float* __restrict__ g3,
    const float* __restrict__ vad_w, const float* __restrict__ vad_b,
    const float* __restrict__ pitch_w, const float* __restrict__ pitch_b,
    float* __restrict__ vad_out,    // (B,T)
    float* __restrict__ pitch_out) {// (B,T,360)
    __shared__ __align__(16) float al[8][392];
    const int b  = blockIdx.y;
    const int t0 = blockIdx.x * 8;
    const int tid = threadIdx.x;   // 0..95

    {
        int tt8 = tid & 7, cg = tid >> 3;    // 8 x 12
        for (int k = cg; k < 96; k += 12)
            al[tt8][k] = xT[((size_t)b * 96 + k) * T_LEN + t0 + tt8];
        const float* gs[3] = {g1, g2, g3};
        for (int i = tid; i < 3 * 8 * 96; i += 96) {
            int plane = i / 768, rem = i % 768, tt = rem / 96;
            al[tt][96 + plane * 96 + tid] =
                gs[plane][((size_t)b * T_LEN + t0 + tt) * 96 + tid];
        }
    }
    __syncthreads();

    const int j0 = tid, j1 = 96 + tid, j2 = 192 + tid;
    const int j3 = (tid < 73) ? 288 + tid : 360;
    const float* w0 = (j0 == 0) ? vad_w : pitch_w + (size_t)(j0 - 1) * 384;
    const float* w1 = pitch_w + (size_t)(j1 - 1) * 384;
    const float* w2 = pitch_w + (size_t)(j2 - 1) * 384;
    const float* w3 = pitch_w + (size_t)(j3 - 1) * 384;
    const float4* w0v = (const float4*)w0;
    const float4* w1v = (const float4*)w1;
    const float4* w2v = (const float4*)w2;
    const float4* w3v = (const float4*)w3;

    f2v acc[4][8];
#pragma unroll
    for (int r = 0; r < 4; ++r)
#pragma unroll
        for (int tt = 0; tt < 8; ++tt) acc[r][tt] = (f2v){0.f, 0.f};

    for (int kc = 0; kc < 96; ++kc) {
        float4 wa = w0v[kc], wb = w1v[kc], wc = w2v[kc], wd = w3v[kc];
        f2v wa0 = {wa.x, wa.y}, wa1 = {wa.z, wa.w};
        f2v wb0 = {wb.x, wb.y}, wb1 = {wb.z, wb.w};
        f2v wc0 = {wc.x, wc.y}, wc1 = {wc.z, wc.w};
        f2v wd0 = {wd.x, wd.y}, wd1 = {wd.z, wd.w};
#pragma unroll
        for (int tt = 0; tt < 8; ++tt) {
            float4 av = *(const float4*)&al[tt][kc * 4];
            f2v a0 = {av.x, av.y}, a1 = {av.z, av.w};
            acc[0][tt] = __builtin_elementwise_fma(wa0, a0, acc[0][tt]);
            acc[0][tt] = __builtin_elementwise_fma(wa1, a1, acc[0][tt]);
            acc[1][tt] = __builtin_elementwise_fma(wb0, a0, acc[1][tt]);
            acc[1][tt] = __builtin_elementwise_fma(wb1, a1, acc[1][tt]);
            acc[2][tt] = __builtin_elementwise_fma(wc0, a0, acc[2][tt]);
            acc[2][tt] = __builtin_elementwise_fma(wc1, a1, acc[2][tt]);
            acc[3][tt] = __builtin_elementwise_fma(wd0, a0, acc[3][tt]);
            acc[3][tt] = __builtin_elementwise_fma(wd1, a1, acc[3][tt]);
        }
    }
    const float bb0 = (j0 == 0) ? vad_b[0] : pitch_b[j0 - 1];
    const float bb1 = pitch_b[j1 - 1];
    const float bb2 = pitch_b[j2 - 1];
    const float bb3 = pitch_b[j3 - 1];
#pragma unroll
    for (int tt = 0; tt < 8; ++tt) {
        size_t t = (size_t)t0 + tt;
        size_t obase = ((size_t)b * T_LEN + t) * NPITCH;
        float v0 = sigmoid_f(acc[0][tt].x + acc[0][tt].y + bb0);
        float v1 = sigmoid_f(acc[1][tt].x + acc[1][tt].y + bb1);
        float v2 = sigmoid_f(acc[2][tt].x + acc[2][tt].y + bb2);
        float v3 = sigmoid_f(acc[3][tt].x + acc[3][tt].y + bb3);
        if (j0 == 0) vad_out[(size_t)b * T_LEN + t] = v0;
        else         pitch_out[obase + j0 - 1] = v0;
        pitch_out[obase + j1 - 1] = v1;
        pitch_out[obase + j2 - 1] = v2;
        if (tid < 73) pitch_out[obase + j3 - 1] = v3;
    }
}

extern "C" void kernel_launch(void* const* d_in, const int* in_sizes, int n_in,
                              void* d_out, int out_size, void* d_ws, size_t ws_size,
                              hipStream_t stream) {
    const float* mel = (const float*)d_in[0];
    const float* c1w = (const float*)d_in[1];
    const float* c1b = (const float*)d_in[2];
    const float* c2w = (const float*)d_in[3];
    const float* c2b = (const float*)d_in[4];
    const float* wih[3] = {(const float*)d_in[5],  (const float*)d_in[9],  (const float*)d_in[13]};
    const float* whh[3] = {(const float*)d_in[6],  (const float*)d_in[10], (const float*)d_in[14]};
    const float* bih[3] = {(const float*)d_in[7],  (const float*)d_in[11], (const float*)d_in[15]};
    const float* bhh[3] = {(const float*)d_in[8],  (const float*)d_in[12], (const float*)d_in[16]};
    const float* vad_w   = (const float*)d_in[17];
    const float* vad_b   = (const float*)d_in[18];
    const float* pitch_w = (const float*)d_in[19];
    const float* pitch_b = (const float*)d_in[20];

    float* out       = (float*)d_out;
    float* vad_out   = out;                          // 128,000
    float* pitch_out = out + 128000;                 // 46,080,000
    float* hout      = out + 128000 + 46080000;      // 3 x 3072

    // workspace: xT | g1 | g2 | g3 (c1T overlaid on g3)
    float* ws  = (float*)d_ws;
    float* xT  = ws;                                 // 12,288,000 floats
    float* g1  = ws + 12288000;
    float* g2  = g1 + 12288000;
    float* g3  = g2 + 12288000;
    float* c1T = g3;                                 // overlay (dead before g3 written)
    // xp + packed weights live in the pitch output region (written only at the end)
    float* xp  = pitch_out;                          // 36,864,000 floats
    float* wpk = pitch_out + 36864000;               // 3 x 27,648 floats

    for (int L = 0; L < 3; ++L)
        pack_whh_kernel<<<108, 256, 0, stream>>>(whh[L], wpk + L * 27648);

    conv1_kernel<<<dim3(63, 32), 256, 0, stream>>>(mel, c1w, c1b, c1T);
    conv2_kernel<<<dim3(63, 32), 256, 0, stream>>>(c1T, c2w, c2b, xT);

    const float* gin[3] = {xT, g1, g2};
    float*       gou[3] = {g1, g2, g3};
    for (int L = 0; L < 3; ++L) {
        xp2_kernel<<<dim3(250, 32), 96, 0, stream>>>(gin[L], wih[L], bih[L], xp, L == 0 ? 1 : 0);
        gru2_kernel<<<32, 192, 0, stream>>>(xp, wpk + L * 27648, bhh[L], gou[L], hout + L * 3072);
    }

    head2_kernel<<<dim3(500, 32), 96, 0, stream>>>(xT, g1, g2, g3,
                                                   vad_w, vad_b, pitch_w, pitch_b,
                                                   vad_out, pitch_out);
}

// Round 3
// 7689.938 us; speedup vs baseline: 1.5599x; 1.3706x over previous
//
#include <hip/hip_runtime.h>

#define T_LEN 4000
#define BATCH 32
#define NMELS 40
#define CONDC 64
#define GRUH  96
#define NPITCH 360

typedef float f2v __attribute__((ext_vector_type(2)));
typedef _Float16 h2v __attribute__((ext_vector_type(2)));

__device__ __forceinline__ float sigmoid_f(float x) {
    return 1.f / (1.f + __expf(-x));
}
__device__ __forceinline__ float tanh_f(float x) {
    return 1.f - 2.f / (1.f + __expf(2.f * x));
}

__device__ __forceinline__ float fdot2(int w, int h, float acc) {
#if __has_builtin(__builtin_amdgcn_fdot2)
    return __builtin_amdgcn_fdot2(__builtin_bit_cast(h2v, w),
                                  __builtin_bit_cast(h2v, h), acc, false);
#else
    h2v wv = __builtin_bit_cast(h2v, w), hv = __builtin_bit_cast(h2v, h);
    return acc + (float)wv.x * (float)hv.x + (float)wv.y * (float)hv.y;
#endif
}

// quad_perm(1,0,3,2) = 0xB1 : lane ^ 1 ; quad_perm(2,3,0,1) = 0x4E : lane ^ 2
__device__ __forceinline__ float dpp_add_xor1(float x) {
    int v = __builtin_amdgcn_mov_dpp(__float_as_int(x), 0xB1, 0xF, 0xF, true);
    return x + __int_as_float(v);
}
__device__ __forceinline__ float dpp_add_xor2(float x) {
    int v = __builtin_amdgcn_mov_dpp(__float_as_int(x), 0x4E, 0xF, 0xF, true);
    return x + __int_as_float(v);
}

__device__ __forceinline__ unsigned int pack2f16(float a, float b) {
    h2v v = {(_Float16)a, (_Float16)b};
    return __builtin_bit_cast(unsigned int, v);
}

// ---------------------------------------------------------------------------
// conv1: mel (B,T,40) -> c1T (B,64,T), causal k=3, tanh
// ---------------------------------------------------------------------------
__global__ void conv1_kernel(const float* __restrict__ mel,
                             const float* __restrict__ w,
                             const float* __restrict__ bias,
                             float* __restrict__ outT) {
    __shared__ float lds[NMELS * 66];
    const int b  = blockIdx.y;
    const int t0 = blockIdx.x * 64;
    const int tid = threadIdx.x;
    for (int idx = tid; idx < 66 * NMELS; idx += 256) {
        int ic = idx % NMELS, trow = idx / NMELS;
        int tg = t0 - 2 + trow;
        float v = (tg >= 0 && tg < T_LEN) ? mel[((size_t)b * T_LEN + tg) * NMELS + ic] : 0.f;
        lds[ic * 66 + trow] = v;
    }
    __syncthreads();
    const int lane = tid & 63;
    const int g = tid >> 6;
    float acc[16];
#pragma unroll
    for (int i = 0; i < 16; ++i) acc[i] = bias[g * 16 + i];
#pragma unroll
    for (int kk = 0; kk < 3; ++kk) {
        for (int ic = 0; ic < NMELS; ++ic) {
            float m = lds[ic * 66 + lane + kk];
#pragma unroll
            for (int i = 0; i < 16; ++i)
                acc[i] = fmaf(w[((g * 16 + i) * NMELS + ic) * 3 + kk], m, acc[i]);
        }
    }
    int t = t0 + lane;
    if (t < T_LEN) {
#pragma unroll
        for (int i = 0; i < 16; ++i)
            outT[((size_t)b * CONDC + g * 16 + i) * T_LEN + t] = tanh_f(acc[i]);
    }
}

// ---------------------------------------------------------------------------
// conv2: c1T (B,64,T) -> xT (B,96,T)
// ---------------------------------------------------------------------------
__global__ void conv2_kernel(const float* __restrict__ inT,
                             const float* __restrict__ w,
                             const float* __restrict__ bias,
                             float* __restrict__ outT) {
    __shared__ float lds[CONDC * 66];
    const int b  = blockIdx.y;
    const int t0 = blockIdx.x * 64;
    const int tid = threadIdx.x;
    for (int idx = tid; idx < 66 * CONDC; idx += 256) {
        int trow = idx % 66, ic = idx / 66;
        int tg = t0 - 2 + trow;
        float v = (tg >= 0 && tg < T_LEN) ? inT[((size_t)b * CONDC + ic) * T_LEN + tg] : 0.f;
        lds[ic * 66 + trow] = v;
    }
    __syncthreads();
    const int lane = tid & 63;
    const int g = tid >> 6;
    float acc[24];
#pragma unroll
    for (int i = 0; i < 24; ++i) acc[i] = bias[g * 24 + i];
#pragma unroll
    for (int kk = 0; kk < 3; ++kk) {
        for (int ic = 0; ic < CONDC; ++ic) {
            float m = lds[ic * 66 + lane + kk];
#pragma unroll
            for (int i = 0; i < 24; ++i)
                acc[i] = fmaf(w[((g * 24 + i) * CONDC + ic) * 3 + kk], m, acc[i]);
        }
    }
    int t = t0 + lane;
    if (t < T_LEN) {
#pragma unroll
        for (int i = 0; i < 24; ++i)
            outT[((size_t)b * GRUH + g * 24 + i) * T_LEN + t] = tanh_f(acc[i]);
    }
}

// ---------------------------------------------------------------------------
// pack layer-1 whh -> f16 half2 blob [192 threads][3 chains][24 half2]
// thread lt: p=lt>>1, kh=lt&1, k-range [kh*48, kh*48+48)
// ---------------------------------------------------------------------------
__global__ void pack1_kernel(const float* __restrict__ whh,
                             unsigned int* __restrict__ out) {
    int e = blockIdx.x * 256 + threadIdx.x;
    if (e >= 192 * 72) return;
    int lt = e / 72, c = (e % 72) / 24, j = e % 24;
    int p = lt >> 1, kh = lt & 1;
    int row = c * 96 + p, k = kh * 48 + 2 * j;
    out[e] = pack2f16(whh[row * 96 + k], whh[row * 96 + k + 1]);
}

// ---------------------------------------------------------------------------
// pack layers 2/3: [384 threads][6 chains][12 half2]
// thread lt: p=lt>>2, kq=lt&3, k-range [kq*24, kq*24+24)
// chains: 0..2 = wih rows {p,96+p,192+p}; 3..5 = whh rows
// ---------------------------------------------------------------------------
__global__ void pack23_kernel(const float* __restrict__ wih,
                              const float* __restrict__ whh,
                              unsigned int* __restrict__ out) {
    int e = blockIdx.x * 256 + threadIdx.x;
    if (e >= 384 * 72) return;
    int lt = e / 72, c = (e % 72) / 12, j = e % 12;
    int p = lt >> 2, kq = lt & 3;
    const float* src = (c < 3) ? wih : whh;
    int row = (c % 3) * 96 + p, k = kq * 24 + 2 * j;
    out[e] = pack2f16(src[row * 96 + k], src[row * 96 + k + 1]);
}

// ---------------------------------------------------------------------------
// xp1 = in @ wih1^T + bih1 -> (B,T,288). (layer-1 only; input transposed)
// ---------------------------------------------------------------------------
__global__ __launch_bounds__(96) void xp2_kernel(
    const float* __restrict__ in,   // (B,96,T)
    const float* __restrict__ wih,  // (288,96)
    const float* __restrict__ bih,
    float* __restrict__ xp) {       // (B,T,288)
    __shared__ __align__(16) float al[16][104];
    const int b  = blockIdx.y;
    const int t0 = blockIdx.x * 16;
    const int tid = threadIdx.x;   // 0..95

    {
        int ttl = tid & 15, cg = tid >> 4;   // 16 x 6
        for (int k = cg; k < 96; k += 6)
            al[ttl][k] = in[((size_t)b * 96 + k) * T_LEN + t0 + ttl];
    }
    __syncthreads();

    const float4* w0 = (const float4*)(wih + (size_t)tid * 96);
    const float4* w1 = (const float4*)(wih + (size_t)(96 + tid) * 96);
    const float4* w2 = (const float4*)(wih + (size_t)(192 + tid) * 96);

    f2v acc[3][16];
#pragma unroll
    for (int r = 0; r < 3; ++r)
#pragma unroll
        for (int tt = 0; tt < 16; ++tt) acc[r][tt] = (f2v){0.f, 0.f};

    for (int kc = 0; kc < 24; ++kc) {
        float4 wa = w0[kc], wb = w1[kc], wc = w2[kc];
        f2v wa0 = {wa.x, wa.y}, wa1 = {wa.z, wa.w};
        f2v wb0 = {wb.x, wb.y}, wb1 = {wb.z, wb.w};
        f2v wc0 = {wc.x, wc.y}, wc1 = {wc.z, wc.w};
#pragma unroll
        for (int tt = 0; tt < 16; ++tt) {
            float4 av = *(const float4*)&al[tt][kc * 4];
            f2v a0 = {av.x, av.y}, a1 = {av.z, av.w};
            acc[0][tt] = __builtin_elementwise_fma(wa0, a0, acc[0][tt]);
            acc[0][tt] = __builtin_elementwise_fma(wa1, a1, acc[0][tt]);
            acc[1][tt] = __builtin_elementwise_fma(wb0, a0, acc[1][tt]);
            acc[1][tt] = __builtin_elementwise_fma(wb1, a1, acc[1][tt]);
            acc[2][tt] = __builtin_elementwise_fma(wc0, a0, acc[2][tt]);
            acc[2][tt] = __builtin_elementwise_fma(wc1, a1, acc[2][tt]);
        }
    }
    float b0 = bih[tid], b1 = bih[96 + tid], b2 = bih[192 + tid];
#pragma unroll
    for (int tt = 0; tt < 16; ++tt) {
        size_t base = ((size_t)b * T_LEN + t0 + tt) * 288;
        xp[base + tid]       = acc[0][tt].x + acc[0][tt].y + b0;
        xp[base + 96 + tid]  = acc[1][tt].x + acc[1][tt].y + b1;
        xp[base + 192 + tid] = acc[2][tt].x + acc[2][tt].y + b2;
    }
}

// ---------------------------------------------------------------------------
// fused 3-layer GRU, wavefront-pipelined. 32 blocks x 960 threads.
// grp0 (192 thr): L1 whh matvec, pairs (p, kh). xp1 from global, 2-deep pf.
// grp1/2 (384 thr each): L2/L3 wih+whh matvecs, quads (p, kq); input layer's
// h buffer in LDS (f16). One lgkm-only barrier per pipeline step.
// ---------------------------------------------------------------------------
#define LOAD12(dst, src) { int4 _a = (src)[0], _b = (src)[1], _c = (src)[2];  \
    (dst)[0]=_a.x; (dst)[1]=_a.y; (dst)[2]=_a.z; (dst)[3]=_a.w;               \
    (dst)[4]=_b.x; (dst)[5]=_b.y; (dst)[6]=_b.z; (dst)[7]=_b.w;               \
    (dst)[8]=_c.x; (dst)[9]=_c.y; (dst)[10]=_c.z; (dst)[11]=_c.w; }

__global__ __launch_bounds__(960, 4) void fused_gru_kernel(
    const float* __restrict__ xp1,     // (B,T,288) incl. bih1
    const int* __restrict__ w1,        // 192*72 dwords (f16x2)
    const int* __restrict__ w2,        // 384*72
    const int* __restrict__ w3,        // 384*72
    const float* __restrict__ bhh1,
    const float* __restrict__ bih2, const float* __restrict__ bhh2,
    const float* __restrict__ bih3, const float* __restrict__ bhh3,
    float* __restrict__ g1, float* __restrict__ g2, float* __restrict__ g3,
    float* __restrict__ hout) {        // 3 x (B,96)
    const int b = blockIdx.x;
    const int tid = threadIdx.x;
    __shared__ __align__(16) _Float16 hb[2][3][96];

    int grp, lt;
    if (tid < 192)      { grp = 0; lt = tid; }
    else if (tid < 576) { grp = 1; lt = tid - 192; }
    else                { grp = 2; lt = tid - 576; }
    const int pp  = (grp == 0) ? (lt >> 1) : (lt >> 2);
    const int sub = (grp == 0) ? (lt & 1) : (lt & 3);

    for (int i = tid; i < 2 * 3 * 96; i += 960) ((_Float16*)hb)[i] = (_Float16)0.f;

    // weights -> VGPRs (pinned)
    int wreg[72];
    {
        const int* wsrc = (grp == 0) ? w1 + lt * 72
                        : (grp == 1) ? w2 + lt * 72 : w3 + lt * 72;
        const int4* wp4 = (const int4*)wsrc;
#pragma unroll
        for (int q = 0; q < 18; ++q) {
            int4 v = wp4[q];
            asm volatile("" : "+v"(v.x), "+v"(v.y), "+v"(v.z), "+v"(v.w));
            wreg[4*q+0] = v.x; wreg[4*q+1] = v.y; wreg[4*q+2] = v.z; wreg[4*q+3] = v.w;
        }
    }

    float b0r = 0.f, b0z = 0.f, b0n = 0.f, b1n = 0.f;
    if (sub == 0) {
        if (grp == 0) { b0r = bhh1[pp]; b0z = bhh1[96+pp]; b0n = bhh1[192+pp]; }
        else {
            const float* bi = (grp == 1) ? bih2 : bih3;
            const float* bh = (grp == 1) ? bhh2 : bhh3;
            b0r = bi[pp] + bh[pp];
            b0z = bi[96+pp] + bh[96+pp];
            b0n = bi[192+pp];
            b1n = bh[192+pp];
        }
    }
    float* gout0 = ((grp == 0) ? g1 : (grp == 1) ? g2 : g3) + (size_t)b * T_LEN * GRUH;
    const float* xpb = xp1 + (size_t)b * T_LEN * 288;

    float hmy = 0.f;
    float xrA = 0.f, xzA = 0.f, xnA = 0.f, xrB = 0.f, xzB = 0.f, xnB = 0.f;
    if (grp == 0 && sub == 0) {
        xrA = xpb[pp];        xzA = xpb[96+pp];        xnA = xpb[192+pp];
        xrB = xpb[288+pp];    xzB = xpb[288+96+pp];    xnB = xpb[288+192+pp];
    }
    __syncthreads();

#define STEP(S, XR, XZ, XN)                                                    \
  {                                                                            \
    const int rp = (S) & 1, wpar = rp ^ 1;                                     \
    if (grp == 0) {                                                            \
      if ((S) < T_LEN) {                                                       \
        const int4* hsrc = (const int4*)&hb[rp][0][sub * 48];                  \
        int hop[24];                                                           \
        LOAD12(hop, hsrc); LOAD12((hop + 12), (hsrc + 3));                     \
        float ar0=0.f, ar1=0.f, az0=0.f, az1=0.f, an0=0.f, an1=0.f;            \
        _Pragma("unroll") for (int j = 0; j < 12; ++j) {                       \
          ar0 = fdot2(wreg[j],      hop[j],      ar0);                         \
          ar1 = fdot2(wreg[12 + j], hop[12 + j], ar1);                         \
          az0 = fdot2(wreg[24 + j], hop[j],      az0);                         \
          az1 = fdot2(wreg[36 + j], hop[12 + j], az1);                         \
          an0 = fdot2(wreg[48 + j], hop[j],      an0);                         \
          an1 = fdot2(wreg[60 + j], hop[12 + j], an1);                         \
        }                                                                      \
        float ar = dpp_add_xor1(ar0 + ar1);                                    \
        float az = dpp_add_xor1(az0 + az1);                                    \
        float an = dpp_add_xor1(an0 + an1);                                    \
        if (sub == 0) {                                                        \
          float r = sigmoid_f((XR) + ar + b0r);                                \
          float z = sigmoid_f((XZ) + az + b0z);                                \
          float n = tanh_f((XN) + r * (an + b0n));                             \
          hmy = n + z * (hmy - n);                                             \
          hb[wpar][0][pp] = (_Float16)hmy;                                     \
          gout0[(size_t)(S) * GRUH + pp] = hmy;                                \
          int tnx = ((S) + 2 <= T_LEN - 1) ? (S) + 2 : T_LEN - 1;              \
          XR = xpb[(size_t)tnx * 288 + pp];                                    \
          XZ = xpb[(size_t)tnx * 288 + 96 + pp];                               \
          XN = xpb[(size_t)tnx * 288 + 192 + pp];                              \
        }                                                                      \
      }                                                                        \
    } else {                                                                   \
      const int t = (S) - grp;                                                 \
      if (t >= 0 && t < T_LEN) {                                               \
        const int lin = grp - 1;                                               \
        const int4* isrc = (const int4*)&hb[rp][lin][sub * 24];                \
        const int4* hsrc = (const int4*)&hb[rp][lin + 1][sub * 24];            \
        int iop[12], hop[12];                                                  \
        LOAD12(iop, isrc); LOAD12(hop, hsrc);                                  \
        float axr=0.f, axz=0.f, axn=0.f, ahr=0.f, ahz=0.f, ahn=0.f;            \
        _Pragma("unroll") for (int j = 0; j < 12; ++j) {                       \
          axr = fdot2(wreg[j],      iop[j], axr);                              \
          axz = fdot2(wreg[12 + j], iop[j], axz);                              \
          axn = fdot2(wreg[24 + j], iop[j], axn);                              \
          ahr = fdot2(wreg[36 + j], hop[j], ahr);                              \
          ahz = fdot2(wreg[48 + j], hop[j], ahz);                              \
          ahn = fdot2(wreg[60 + j], hop[j], ahn);                              \
        }                                                                      \
        float pr  = dpp_add_xor2(dpp_add_xor1(axr + ahr));                     \
        float pz  = dpp_add_xor2(dpp_add_xor1(axz + ahz));                     \
        float pxn = dpp_add_xor2(dpp_add_xor1(axn));                           \
        float phn = dpp_add_xor2(dpp_add_xor1(ahn));                           \
        if (sub == 0) {                                                        \
          float r = sigmoid_f(pr + b0r);                                       \
          float z = sigmoid_f(pz + b0z);                                       \
          float n = tanh_f(pxn + b0n + r * (phn + b1n));                       \
          hmy = n + z * (hmy - n);                                             \
          hb[wpar][lin + 1][pp] = (_Float16)hmy;                               \
          gout0[(size_t)t * GRUH + pp] = hmy;                                  \
        }                                                                      \
      }                                                                        \
    }                                                                          \
    asm volatile("s_waitcnt lgkmcnt(0)" ::: "memory");                         \
    __builtin_amdgcn_s_barrier();                                              \
    asm volatile("" ::: "memory");                                             \
  }

    for (int s = 0; s < T_LEN + 2; s += 2) {
        STEP(s,     xrA, xzA, xnA);
        STEP(s + 1, xrB, xzB, xnB);
    }
#undef STEP

    if (sub == 0) hout[grp * (BATCH * GRUH) + b * GRUH + pp] = hmy;
}

// ---------------------------------------------------------------------------
// head: cat=[x,g1,g2,g3] (384); 96 threads, 4 rows/thread, tile tt=8.
// ---------------------------------------------------------------------------
__global__ __launch_bounds__(96) void head2_kernel(
    const float* __restrict__ xT,   // (B,96,T)
    const float* __restrict__ g1,   // (B,T,96)
    const float* __restrict__ g2,
    const float* __restrict__ g3,
    const float* __restrict__ vad_w, const float* __restrict__ vad_b,
    const float* __restrict__ pitch_w, const float* __restrict__ pitch_b,
    float* __restrict__ vad_out,    // (B,T)
    float* __restrict__ pitch_out) {// (B,T,360)
    __shared__ __align__(16) float al[8][392];
    const int b  = blockIdx.y;
    const int t0 = blockIdx.x * 8;
    const int tid = threadIdx.x;   // 0..95

    {
        int tt8 = tid & 7, cg = tid >> 3;    // 8 x 12
        for (int k = cg; k < 96; k += 12)
            al[tt8][k] = xT[((size_t)b * 96 + k) * T_LEN + t0 + tt8];
        const float* gs[3] = {g1, g2, g3};
        for (int i = tid; i < 3 * 8 * 96; i += 96) {
            int plane = i / 768, rem = i % 768, tt = rem / 96;
            al[tt][96 + plane * 96 + tid] =
                gs[plane][((size_t)b * T_LEN + t0 + tt) * 96 + tid];
        }
    }
    __syncthreads();

    const int j0 = tid, j1 = 96 + tid, j2 = 192 + tid;
    const int j3 = (tid < 73) ? 288 + tid : 360;
    const float* w0 = (j0 == 0) ? vad_w : pitch_w + (size_t)(j0 - 1) * 384;
    const float* w1 = pitch_w + (size_t)(j1 - 1) * 384;
    const float* w2 = pitch_w + (size_t)(j2 - 1) * 384;
    const float* w3 = pitch_w + (size_t)(j3 - 1) * 384;
    const float4* w0v = (const float4*)w0;
    const float4* w1v = (const float4*)w1;
    const float4* w2v = (const float4*)w2;
    const float4* w3v = (const float4*)w3;

    f2v acc[4][8];
#pragma unroll
    for (int r = 0; r < 4; ++r)
#pragma unroll
        for (int tt = 0; tt < 8; ++tt) acc[r][tt] = (f2v){0.f, 0.f};

    for (int kc = 0; kc < 96; ++kc) {
        float4 wa = w0v[kc], wb = w1v[kc], wc = w2v[kc], wd = w3v[kc];
        f2v wa0 = {wa.x, wa.y}, wa1 = {wa.z, wa.w};
        f2v wb0 = {wb.x, wb.y}, wb1 = {wb.z, wb.w};
        f2v wc0 = {wc.x, wc.y}, wc1 = {wc.z, wc.w};
        f2v wd0 = {wd.x, wd.y}, wd1 = {wd.z, wd.w};
#pragma unroll
        for (int tt = 0; tt < 8; ++tt) {
            float4 av = *(const float4*)&al[tt][kc * 4];
            f2v a0 = {av.x, av.y}, a1 = {av.z, av.w};
            acc[0][tt] = __builtin_elementwise_fma(wa0, a0, acc[0][tt]);
            acc[0][tt] = __builtin_elementwise_fma(wa1, a1, acc[0][tt]);
            acc[1][tt] = __builtin_elementwise_fma(wb0, a0, acc[1][tt]);
            acc[1][tt] = __builtin_elementwise_fma(wb1, a1, acc[1][tt]);
            acc[2][tt] = __builtin_elementwise_fma(wc0, a0, acc[2][tt]);
            acc[2][tt] = __builtin_elementwise_fma(wc1, a1, acc[2][tt]);
            acc[3][tt] = __builtin_elementwise_fma(wd0, a0, acc[3][tt]);
            acc[3][tt] = __builtin_elementwise_fma(wd1, a1, acc[3][tt]);
        }
    }
    const float bb0 = (j0 == 0) ? vad_b[0] : pitch_b[j0 - 1];
    const float bb1 = pitch_b[j1 - 1];
    const float bb2 = pitch_b[j2 - 1];
    const float bb3 = pitch_b[j3 - 1];
#pragma unroll
    for (int tt = 0; tt < 8; ++tt) {
        size_t t = (size_t)t0 + tt;
        size_t obase = ((size_t)b * T_LEN + t) * NPITCH;
        float v0 = sigmoid_f(acc[0][tt].x + acc[0][tt].y + bb0);
        float v1 = sigmoid_f(acc[1][tt].x + acc[1][tt].y + bb1);
        float v2 = sigmoid_f(acc[2][tt].x + acc[2][tt].y + bb2);
        float v3 = sigmoid_f(acc[3][tt].x + acc[3][tt].y + bb3);
        if (j0 == 0) vad_out[(size_t)b * T_LEN + t] = v0;
        else         pitch_out[obase + j0 - 1] = v0;
        pitch_out[obase + j1 - 1] = v1;
        pitch_out[obase + j2 - 1] = v2;
        if (tid < 73) pitch_out[obase + j3 - 1] = v3;
    }
}

extern "C" void kernel_launch(void* const* d_in, const int* in_sizes, int n_in,
                              void* d_out, int out_size, void* d_ws, size_t ws_size,
                              hipStream_t stream) {
    const float* mel = (const float*)d_in[0];
    const float* c1w = (const float*)d_in[1];
    const float* c1b = (const float*)d_in[2];
    const float* c2w = (const float*)d_in[3];
    const float* c2b = (const float*)d_in[4];
    const float* wih[3] = {(const float*)d_in[5],  (const float*)d_in[9],  (const float*)d_in[13]};
    const float* whh[3] = {(const float*)d_in[6],  (const float*)d_in[10], (const float*)d_in[14]};
    const float* bih[3] = {(const float*)d_in[7],  (const float*)d_in[11], (const float*)d_in[15]};
    const float* bhh[3] = {(const float*)d_in[8],  (const float*)d_in[12], (const float*)d_in[16]};
    const float* vad_w   = (const float*)d_in[17];
    const float* vad_b   = (const float*)d_in[18];
    const float* pitch_w = (const float*)d_in[19];
    const float* pitch_b = (const float*)d_in[20];

    float* out       = (float*)d_out;
    float* vad_out   = out;                          // 128,000
    float* pitch_out = out + 128000;                 // 46,080,000
    float* hout      = out + 128000 + 46080000;      // 3 x 3072

    float* ws  = (float*)d_ws;
    float* xT  = ws;                                 // 12,288,000 floats
    float* g1  = ws + 12288000;
    float* g2  = g1 + 12288000;
    float* g3  = g2 + 12288000;
    float* c1T = g3;                                 // overlay (dead before g3 written)
    float* xp  = pitch_out;                          // 36,864,000 floats (scratch)
    unsigned int* wpk1 = (unsigned int*)(pitch_out + 36864000);  // 13,824 dwords
    unsigned int* wpk2 = wpk1 + 192 * 72;                        // 27,648
    unsigned int* wpk3 = wpk2 + 384 * 72;                        // 27,648

    pack1_kernel<<<54, 256, 0, stream>>>(whh[0], wpk1);
    pack23_kernel<<<108, 256, 0, stream>>>(wih[1], whh[1], wpk2);
    pack23_kernel<<<108, 256, 0, stream>>>(wih[2], whh[2], wpk3);

    conv1_kernel<<<dim3(63, 32), 256, 0, stream>>>(mel, c1w, c1b, c1T);
    conv2_kernel<<<dim3(63, 32), 256, 0, stream>>>(c1T, c2w, c2b, xT);

    xp2_kernel<<<dim3(250, 32), 96, 0, stream>>>(xT, wih[0], bih[0], xp);

    fused_gru_kernel<<<32, 960, 0, stream>>>(
        xp, (const int*)wpk1, (const int*)wpk2, (const int*)wpk3,
        bhh[0], bih[1], bhh[1], bih[2], bhh[2], g1, g2, g3, hout);

    head2_kernel<<<dim3(500, 32), 96, 0, stream>>>(xT, g1, g2, g3,
                                                   vad_w, vad_b, pitch_w, pitch_b,
                                                   vad_out, pitch_out);
}